// Round 4
// baseline (861.304 us; speedup 1.0000x reference)
//
#include <hip/hip_runtime.h>
#include <hip/hip_bf16.h>

typedef __attribute__((ext_vector_type(8))) short short8;
typedef __attribute__((ext_vector_type(4))) float f32x4;
typedef __attribute__((ext_vector_type(8))) unsigned short u16x8;

#define LOG2E 1.4426950408889634f

__device__ __forceinline__ unsigned pk2(float a, float b) {
  __hip_bfloat162 h = __float22bfloat162_rn(float2{a, b});
  return *reinterpret_cast<unsigned*>(&h);
}
__device__ __forceinline__ unsigned short f2bf(float f) {
  __hip_bfloat16 h = __float2bfloat16(f);
  return *reinterpret_cast<unsigned short*>(&h);
}

// ---------------------------------------------------------------------------
// QKV projection (round-2 passing version, unchanged):
// out_z[m,n] = sum_k X[m,k]*Wz[n,k]; Q pre-scaled by 1/32 (exact in bf16).
// grid (32 mt, 8 nt, 3 z), block 256 (4 waves 2x2, wave owns 64x64)
// ---------------------------------------------------------------------------
__global__ __launch_bounds__(256, 3) void qkv_proj(
    const float* __restrict__ X, const float* __restrict__ Wq,
    const float* __restrict__ Wk, const float* __restrict__ Wv,
    unsigned short* __restrict__ ws) {
  const int mt = blockIdx.x, nt = blockIdx.y, z = blockIdx.z;
  const float* __restrict__ W = (z == 0) ? Wq : (z == 1) ? Wk : Wv;
  unsigned short* __restrict__ out = ws + (size_t)z * 4096 * 1024;
  const float osc = (z == 0) ? 0.03125f : 1.0f;

  __shared__ unsigned short As[128][72];
  __shared__ unsigned short Bs[128][72];

  const int tid = threadIdx.x;
  const int wave = tid >> 6, lane = tid & 63;
  const int lq = lane & 15, lg = lane >> 4;
  const int wr = wave >> 1, wc = wave & 1;

  f32x4 acc[4][4] = {};
  const int srow = tid >> 4;
  const int sc4 = (tid & 15) * 4;

  for (int kt = 0; kt < 1024; kt += 64) {
#pragma unroll
    for (int i = 0; i < 8; ++i) {
      const int row = srow + 16 * i;
      float4 a = *(const float4*)(X + (size_t)(mt * 128 + row) * 1024 + kt + sc4);
      float4 b = *(const float4*)(W + (size_t)(nt * 128 + row) * 1024 + kt + sc4);
      *(uint2*)&As[row][sc4] = make_uint2(pk2(a.x, a.y), pk2(a.z, a.w));
      *(uint2*)&Bs[row][sc4] = make_uint2(pk2(b.x, b.y), pk2(b.z, b.w));
    }
    __syncthreads();
#pragma unroll
    for (int ks = 0; ks < 2; ++ks) {
      short8 af[4], bf[4];
#pragma unroll
      for (int i = 0; i < 4; ++i) {
        af[i] = *(const short8*)&As[wr * 64 + i * 16 + lq][ks * 32 + lg * 8];
        bf[i] = *(const short8*)&Bs[wc * 64 + i * 16 + lq][ks * 32 + lg * 8];
      }
#pragma unroll
      for (int i = 0; i < 4; ++i)
#pragma unroll
        for (int j = 0; j < 4; ++j)
          acc[i][j] = __builtin_amdgcn_mfma_f32_16x16x32_bf16(af[i], bf[j], acc[i][j], 0, 0, 0);
    }
    __syncthreads();
  }
#pragma unroll
  for (int i = 0; i < 4; ++i)
#pragma unroll
    for (int j = 0; j < 4; ++j)
#pragma unroll
      for (int r = 0; r < 4; ++r) {
        const int row = mt * 128 + wr * 64 + i * 16 + lg * 4 + r;
        const int col = nt * 128 + wc * 64 + j * 16 + lq;
        out[(size_t)row * 1024 + col] = f2bf(acc[i][j][r] * osc);
      }
}

// ---------------------------------------------------------------------------
// Attention per (b,h). Q',K',V' contiguous [2048,64] bf16 (seq-split view).
// QK^T fragments loaded DIRECTLY from global (K-tile is L1-resident; 64B
// segments) -> pass 1 has no LDS and no barriers. Fixed-shift softmax (c=0).
// Pass 2: VT stage (LDS) + per-n QK recompute + NT float4 P stores + PV.
// grid 512 (bh = blk&31 -> same-head wgs share an XCD L2), block 512.
// ---------------------------------------------------------------------------
__global__ __launch_bounds__(512, 4) void mha_attn(
    const unsigned short* __restrict__ ws, float* __restrict__ out) {
  const int qb = blockIdx.x >> 5;
  const int bh = blockIdx.x & 31;
  const int b = bh >> 4, h = bh & 15;

  const unsigned short* __restrict__ Qg = ws + ((size_t)b * 2048 + h * 128) * 1024;
  const unsigned short* __restrict__ Kg = Qg + (size_t)4096 * 1024;
  const unsigned short* __restrict__ Vg = Qg + (size_t)2 * 4096 * 1024;

  float* __restrict__ simout =
      out + (size_t)4194304 + ((size_t)bh * 2048 + (size_t)qb * 128) * 2048;
  float* __restrict__ attnout = out + (size_t)b * 2048 * 1024 + h * 64;

  __shared__ unsigned short VTs[64][136];    // V^T [d][k], +8 pad
  __shared__ unsigned short Ps[8][16][136];  // per-wave P strip [q][k]

  const int tid = threadIdx.x;
  const int wave = tid >> 6, lane = tid & 63;
  const int lq = lane & 15, lg = lane >> 4;

  short8 qf[2];  // B-operand: this wave's 16 q-rows
  {
    const unsigned short* qrow = Qg + (size_t)(qb * 128 + wave * 16 + lq) * 64;
    qf[0] = *(const short8*)(qrow + lg * 8);
    qf[1] = *(const short8*)(qrow + 32 + lg * 8);
  }

  // per-lane K-fragment base: row lq (of each 16-row n-subtile), k-cols lg*8..
  const unsigned short* Kfrag = Kg + (size_t)lq * 64 + lg * 8;

  // ---------------- pass 1: l = sum exp(s); no LDS, no barriers ----------
  float lacc = 0.f;
  for (int kt = 0; kt < 16; ++kt) {
    const unsigned short* kb = Kfrag + (size_t)kt * 8192;
#pragma unroll
    for (int n = 0; n < 8; ++n) {
      f32x4 a = {};
      short8 k0 = *(const short8*)(kb + n * 1024);
      a = __builtin_amdgcn_mfma_f32_16x16x32_bf16(k0, qf[0], a, 0, 0, 0);
      short8 k1 = *(const short8*)(kb + n * 1024 + 32);
      a = __builtin_amdgcn_mfma_f32_16x16x32_bf16(k1, qf[1], a, 0, 0, 0);
      lacc += (__builtin_amdgcn_exp2f(a[0] * LOG2E) + __builtin_amdgcn_exp2f(a[1] * LOG2E)) +
              (__builtin_amdgcn_exp2f(a[2] * LOG2E) + __builtin_amdgcn_exp2f(a[3] * LOG2E));
    }
  }
  lacc += __shfl_xor(lacc, 16);
  lacc += __shfl_xor(lacc, 32);
  const float nl2l = -__log2f(lacc);  // p = exp2(s*LOG2E - log2 l)

  // ---------------- pass 2: P write + PV ----------------
  const int vk0 = (tid >> 3) * 2, vcg = (tid & 7) * 8;
  const unsigned short* Vbase = Vg + (size_t)vk0 * 64 + vcg;
  u16x8 vp0 = *(const u16x8*)(Vbase);
  u16x8 vp1 = *(const u16x8*)(Vbase + 64);

  f32x4 oacc[4] = {};
  for (int kt = 0; kt < 16; ++kt) {
#pragma unroll
    for (int j = 0; j < 8; ++j) {  // VT stage: pack rows vk0, vk0+1
      unsigned val = (unsigned)(unsigned short)vp0[j] |
                     ((unsigned)(unsigned short)vp1[j] << 16);
      *(unsigned*)&VTs[vcg + j][vk0] = val;
    }
    __syncthreads();
    if (kt < 15) {  // T14 issue-early: latency hides under QK+PV
      vp0 = *(const u16x8*)(Vbase + (kt + 1) * 8192);
      vp1 = *(const u16x8*)(Vbase + (kt + 1) * 8192 + 64);
    }
    const unsigned short* kb = Kfrag + (size_t)kt * 8192;
    float* simrow = simout + (size_t)(wave * 16 + lq) * 2048 + kt * 128 + lg * 4;
#pragma unroll
    for (int n = 0; n < 8; ++n) {
      f32x4 a = {};
      short8 k0 = *(const short8*)(kb + n * 1024);
      a = __builtin_amdgcn_mfma_f32_16x16x32_bf16(k0, qf[0], a, 0, 0, 0);
      short8 k1 = *(const short8*)(kb + n * 1024 + 32);
      a = __builtin_amdgcn_mfma_f32_16x16x32_bf16(k1, qf[1], a, 0, 0, 0);
      f32x4 p;
      p[0] = __builtin_amdgcn_exp2f(__builtin_fmaf(a[0], LOG2E, nl2l));
      p[1] = __builtin_amdgcn_exp2f(__builtin_fmaf(a[1], LOG2E, nl2l));
      p[2] = __builtin_amdgcn_exp2f(__builtin_fmaf(a[2], LOG2E, nl2l));
      p[3] = __builtin_amdgcn_exp2f(__builtin_fmaf(a[3], LOG2E, nl2l));
      __builtin_nontemporal_store(p, (f32x4*)(simrow + n * 16));
      *(uint2*)&Ps[wave][lq][n * 16 + lg * 4] = make_uint2(pk2(p[0], p[1]), pk2(p[2], p[3]));
    }
    // PV: O[q,d] += P[q,k] V[k,d]
#pragma unroll
    for (int ks = 0; ks < 4; ++ks) {
      short8 pf = *(const short8*)&Ps[wave][lq][ks * 32 + lg * 8];
#pragma unroll
      for (int d = 0; d < 4; ++d) {
        short8 vf = *(const short8*)&VTs[d * 16 + lq][ks * 32 + lg * 8];
        oacc[d] = __builtin_amdgcn_mfma_f32_16x16x32_bf16(pf, vf, oacc[d], 0, 0, 0);
      }
    }
    __syncthreads();
  }
#pragma unroll
  for (int d = 0; d < 4; ++d)
#pragma unroll
    for (int r = 0; r < 4; ++r) {
      __builtin_nontemporal_store(
          oacc[d][r],
          attnout + (size_t)(qb * 128 + wave * 16 + lg * 4 + r) * 1024 + d * 16 + lq);
    }
}

extern "C" void kernel_launch(void* const* d_in, const int* in_sizes, int n_in,
                              void* d_out, int out_size, void* d_ws, size_t ws_size,
                              hipStream_t stream) {
  const float* X  = (const float*)d_in[0];
  const float* Wq = (const float*)d_in[1];
  const float* Wk = (const float*)d_in[2];
  const float* Wv = (const float*)d_in[3];
  unsigned short* ws = (unsigned short*)d_ws;  // 24 MiB used
  float* out = (float*)d_out;

  qkv_proj<<<dim3(32, 8, 3), 256, 0, stream>>>(X, Wq, Wk, Wv, ws);
  mha_attn<<<dim3(512), 512, 0, stream>>>(ws, out);
}